// Round 8
// baseline (179.489 us; speedup 1.0000x reference)
//
#include <hip/hip_runtime.h>
#include <math.h>

// B=2, S=2048, D_IN=1024, H=16, DA=DH=64, EMBED=1024, KSIZE=1 (conv == GEMM)

typedef __bf16 bf16;
typedef __bf16 bf16x8 __attribute__((ext_vector_type(8)));
typedef __bf16 bf16x4 __attribute__((ext_vector_type(4)));
typedef float  f32x4  __attribute__((ext_vector_type(4)));
typedef float  f32x16 __attribute__((ext_vector_type(16)));

#define MFMA16(a, b, c) __builtin_amdgcn_mfma_f32_16x16x32_bf16((a), (b), (c), 0, 0, 0)
#define MFMA32(a, b, c) __builtin_amdgcn_mfma_f32_32x32x16_bf16((a), (b), (c), 0, 0, 0)

__device__ __forceinline__ void gll16(const void* g, void* l) {
    __builtin_amdgcn_global_load_lds(
        (__attribute__((address_space(1))) unsigned int*)g,
        (__attribute__((address_space(3))) unsigned int*)l, 16, 0, 0);
}

__device__ __forceinline__ unsigned int cvt_pk_bf16(float lo, float hi) {
    unsigned int r;
    asm("v_cvt_pk_bf16_f32 %0, %1, %2" : "=v"(r) : "v"(lo), "v"(hi));
    return r;
}

// ---------------------------------------------------------------------------
// fp32->bf16 convert; wq gets 0.125*log2(e) folded (attn uses exp2).
// ---------------------------------------------------------------------------
__global__ __launch_bounds__(256) void cvt_all_kernel(
    const float* __restrict__ x,  const float* __restrict__ wq,
    const float* __restrict__ wk, const float* __restrict__ wv,
    const float* __restrict__ wo,
    bf16* __restrict__ xb,  bf16* __restrict__ wqb, bf16* __restrict__ wkb,
    bf16* __restrict__ wvb, bf16* __restrict__ wob)
{
    #pragma unroll
    for (int k = 0; k < 4; k++) {
        const int blk = blockIdx.x * 4 + k;   // 0..8191 virtual block
        const float* src; bf16* dst; int off; float scale = 1.f;
        if (blk < 4096)      { src = x;  dst = xb;  off = blk * 1024; }
        else if (blk < 5120) { src = wq; dst = wqb; off = (blk - 4096) * 1024;
                               scale = 0.18033688011112042f; }  // 0.125*log2(e)
        else if (blk < 6144) { src = wk; dst = wkb; off = (blk - 5120) * 1024; }
        else if (blk < 7168) { src = wv; dst = wvb; off = (blk - 6144) * 1024; }
        else                 { src = wo; dst = wob; off = (blk - 7168) * 1024; }
        const int i = off + threadIdx.x * 4;
        f32x4 v = *(const f32x4*)(src + i);
        bf16x4 o;
        o[0] = (bf16)(v[0] * scale); o[1] = (bf16)(v[1] * scale);
        o[2] = (bf16)(v[2] * scale); o[3] = (bf16)(v[3] * scale);
        *(bf16x4*)(dst + i) = o;
    }
}

// ---------------------------------------------------------------------------
// QKV GEMM, double-buffered 2-phase, 128x128 tile, BK=32, 3 blocks/CU.
// LDS XOR swizzle granule' = q ^ ((row>>1)&3) on staging src + reads.
// ---------------------------------------------------------------------------
__global__ __launch_bounds__(256, 3) void qkv_mfma_kernel(
    const bf16* __restrict__ xb, const bf16* __restrict__ wqb,
    const bf16* __restrict__ wkb, const bf16* __restrict__ wvb,
    bf16* __restrict__ Qb, bf16* __restrict__ Kb, bf16* __restrict__ Vtb)
{
    __shared__ bf16 As[2][128 * 32];
    __shared__ bf16 Bs[2][128 * 32];
    // bijective XCD-chunk remap (768 = 8 XCD * 96 blocks)
    const int lin = blockIdx.x + 32 * blockIdx.y;   // dispatch-linear id
    const int xcd = lin & 7, lid = lin >> 3;        // xcd = hw XCD (id % 8)
    const int rem = xcd * 96 + lid;                 // contiguous per XCD
    const int mt = rem & 31;                        // 32 row tiles
    const int nt = rem >> 5;                        // 24 = which*8 + coltile
    const int which = nt >> 3;
    const bf16* Wm = (which == 0) ? wqb : (which == 1) ? wkb : wvb;

    const int t = threadIdx.x;
    const int w = t >> 6, lane = t & 63, quad = lane >> 4, l16 = lane & 15;
    const int wm = (w >> 1) * 64, wn = (w & 1) * 64;
    const int srow = lane >> 2;
    const int scol = ((lane & 3) ^ ((lane >> 3) & 3)) * 8;
    const int gx = (l16 >> 1) & 3;        // read-side XOR term

    const bf16* Ab = xb + ((size_t)(mt * 128) + srow) * 1024;
    const bf16* Bb = Wm + ((size_t)((nt & 7) * 128) + srow) * 1024;

    f32x4 acc[4][4];
    #pragma unroll
    for (int i = 0; i < 4; i++)
        #pragma unroll
        for (int j = 0; j < 4; j++)
            #pragma unroll
            for (int r = 0; r < 4; r++) acc[i][j][r] = 0.f;

    gll16(Ab + (size_t)(w * 16) * 1024 + scol,       As[0] + w * 512);
    gll16(Ab + (size_t)((w + 4) * 16) * 1024 + scol, As[0] + (w + 4) * 512);
    gll16(Bb + (size_t)(w * 16) * 1024 + scol,       Bs[0] + w * 512);
    gll16(Bb + (size_t)((w + 4) * 16) * 1024 + scol, Bs[0] + (w + 4) * 512);

    for (int it = 0; it < 32; it++) {
        const int cur = it & 1, nxt = cur ^ 1;
        __syncthreads();
        if (it < 31) {
            const int kn = it * 32 + 32;
            gll16(Ab + (size_t)(w * 16) * 1024 + kn + scol,       As[nxt] + w * 512);
            gll16(Ab + (size_t)((w + 4) * 16) * 1024 + kn + scol, As[nxt] + (w + 4) * 512);
            gll16(Bb + (size_t)(w * 16) * 1024 + kn + scol,       Bs[nxt] + w * 512);
            gll16(Bb + (size_t)((w + 4) * 16) * 1024 + kn + scol, Bs[nxt] + (w + 4) * 512);
        }
        bf16x8 af[4], bfr[4];
        #pragma unroll
        for (int i = 0; i < 4; i++)
            af[i] = *(const bf16x8*)&As[cur][(wm + i * 16 + l16) * 32 +
                                             (quad ^ gx) * 8];
        #pragma unroll
        for (int j = 0; j < 4; j++)
            bfr[j] = *(const bf16x8*)&Bs[cur][(wn + j * 16 + l16) * 32 +
                                              (quad ^ gx) * 8];
        #pragma unroll
        for (int i = 0; i < 4; i++)
            #pragma unroll
            for (int j = 0; j < 4; j++)
                acc[i][j] = MFMA16(af[i], bfr[j], acc[i][j]);
    }

    const int nbase = (nt & 7) * 128 + wn;
    if (which == 2) {
        #pragma unroll
        for (int i = 0; i < 4; i++) {
            const int m0 = mt * 128 + wm + i * 16 + quad * 4;
            const int bb = m0 >> 11, s0 = m0 & 2047;
            #pragma unroll
            for (int j = 0; j < 4; j++) {
                const int n = nbase + j * 16 + l16;
                const int h = n >> 6, d = n & 63;
                bf16x4 pk;
                #pragma unroll
                for (int r = 0; r < 4; r++) pk[r] = (bf16)acc[i][j][r];
                *(bf16x4*)&Vtb[(((size_t)(bb * 16 + h)) * 64 + d) * 2048 + s0] = pk;
            }
        }
    } else {
        bf16* Out = (which == 0) ? Qb : Kb;
        #pragma unroll
        for (int i = 0; i < 4; i++) {
            #pragma unroll
            for (int r = 0; r < 4; r++) {
                const int m = mt * 128 + wm + i * 16 + quad * 4 + r;
                const int bb = m >> 11, s = m & 2047;
                #pragma unroll
                for (int j = 0; j < 4; j++) {
                    const int n = nbase + j * 16 + l16;
                    const int h = n >> 6, d = n & 63;
                    Out[(((size_t)(bb * 16 + h)) * 2048 + s) * 64 + d] =
                        (bf16)acc[i][j][r];
                }
            }
        }
    }
}

// ---------------------------------------------------------------------------
// Attention v10: v9 engine (32x32x16 MFMA, in-register P via cvt_pk +
// permlane32_swap, unchanged) + load-balance remap.
// R7 evidence: v9 engine is ~2x cheaper per unit but attn time didn't move
// -> straggler CUs with two high-t blocks (co-residency pairs adjacent
// XCD-local ids (i, i^1), which had equal t in the R7 map).
// New map: xcd=g&7, i=g>>3, bh=xcd*4+((i>>4)&3), t_raw=(i>>1)&7,
// t = ((i&1)^((i>>5)&1)) ? 15-t_raw : t_raw.
// Complementary (t, 15-t) under BOTH (i,i^1) AND (i,i+32) packings ->
// any such co-resident pair sums to 17 iters. Bijective per XCD
// (4 bh x 16 t); bh stays XCD-resident for K/V L2 locality.
// LDS: Ks[2][128x64] + Vts[2][64x128] = 64KB -> 2 blocks/CU.
// ---------------------------------------------------------------------------
__global__ __launch_bounds__(256, 2) void attn_mfma_kernel(
    const bf16* __restrict__ Qb, const bf16* __restrict__ Kb,
    const bf16* __restrict__ Vtb, bf16* __restrict__ ctxb)
{
    __shared__ bf16 Ks[2][128 * 64];      // 128 keys x 64 d (row=key, 128B)
    __shared__ bf16 Vts[2][64 * 128];     // 64 d x 128 keys (row=d, 256B)

    const int g = blockIdx.x;             // 512
    const int xcd = g & 7, i = g >> 3;    // XCD-local index i in 0..63
    const int bh = xcd * 4 + ((i >> 4) & 3);
    const int t_raw = (i >> 1) & 7;
    const int t = ((i & 1) ^ ((i >> 5) & 1)) ? (15 - t_raw) : t_raw;
    const int h = bh & 15, b = bh >> 4;
    const int tid = threadIdx.x;
    const int w = tid >> 6, lane = tid & 63;
    const int l32 = lane & 31, hv = lane >> 5;

    const size_t hb = (size_t)(b * 16 + h);
    const bf16* Qh = Qb + hb * (2048 * 64);
    const bf16* Kh = Kb + hb * (2048 * 64);
    const bf16* Vh = Vtb + hb * (64 * 2048);

    const int qrow = t * 128 + w * 32 + l32;  // lane's q-row (B-col / mask ref)

    // Q B-frags (kt-invariant): frag ks covers k(d) = ks*16 + hv*8 + e
    bf16x8 qf[4];
    #pragma unroll
    for (int ks = 0; ks < 4; ks++)
        qf[ks] = *(const bf16x8*)(Qh + (size_t)qrow * 64 + ks * 16 + hv * 8);

    f32x16 o0, o1, zero16;
    #pragma unroll
    for (int r = 0; r < 16; r++) { o0[r] = 0.f; o1[r] = 0.f; zero16[r] = 0.f; }
    float lacc = 0.f;

    // staging lanes
    const int ksr = lane >> 3, ksc = lane & 7;    // K chunk: 8 rows x 8 pos(16B)
    const int vsr = lane >> 4, vsc = lane & 15;   // V chunk: 4 rows x 16 pos(16B)

    #define STAGE(ktv, buf)                                                   \
        {                                                                     \
            _Pragma("unroll")                                                 \
            for (int j = 0; j < 4; j++) {                                     \
                const int c = 4 * w + j;                                      \
                const int kr = c * 8 + ksr;                                   \
                gll16(Kh + (size_t)((ktv) * 128 + kr) * 64 +                  \
                          ((ksc ^ (kr & 7)) * 8),                             \
                      Ks[buf] + c * 512);                                     \
                const int vr = c * 4 + vsr;                                   \
                gll16(Vh + (size_t)vr * 2048 + (ktv) * 128 +                  \
                          ((vsc ^ (vr & 15)) * 8),                            \
                      Vts[buf] + c * 512);                                    \
            }                                                                 \
        }

    STAGE(0, 0);

    for (int v = 0; v <= t; v++) {
        const int cur = v & 1;
        __syncthreads();                  // staging for cur drained; nxt free
        if (v < t) STAGE(v + 1, cur ^ 1);
        const bool diag = (v == t);

        // QK^T: S[key 0..127][q 0..31] for this wave's 32 q-rows
        f32x16 sacc[4];
        const int rowx = l32 & 7;
        __builtin_amdgcn_s_setprio(1);
        #pragma unroll
        for (int c = 0; c < 4; c++) {
            const int key = c * 32 + l32;
            bf16x8 kf0 = *(const bf16x8*)&Ks[cur][key * 64 + ((hv ^ rowx) * 8)];
            sacc[c] = MFMA32(kf0, qf[0], zero16);
            #pragma unroll
            for (int ks = 1; ks < 4; ks++) {
                bf16x8 kf = *(const bf16x8*)&Ks[cur][key * 64 +
                                (((ks * 2 + hv) ^ rowx) * 8)];
                sacc[c] = MFMA32(kf, qf[ks], sacc[c]);
            }
        }
        __builtin_amdgcn_s_setprio(0);

        // exp2 + causal mask (diag tile only) + per-lane lsum partial
        #pragma unroll
        for (int c = 0; c < 4; c++) {
            #pragma unroll
            for (int r = 0; r < 16; r++) {
                float p = __builtin_amdgcn_exp2f(sacc[c][r]);
                if (diag) {
                    const int key = v * 128 + c * 32 + (r & 3) + 8 * (r >> 2)
                                    + 4 * hv;
                    if (key > qrow) p = 0.f;
                }
                sacc[c][r] = p;
                lacc += p;
            }
        }

        // PV: per 16-key chunk build A-frag in registers, 2 V-frags, 2 MFMA
        __builtin_amdgcn_s_setprio(1);
        #pragma unroll
        for (int c = 0; c < 4; c++) {
            #pragma unroll
            for (int hh = 0; hh < 2; hh++) {
                unsigned int W0 = cvt_pk_bf16(sacc[c][8 * hh + 0], sacc[c][8 * hh + 1]);
                unsigned int W1 = cvt_pk_bf16(sacc[c][8 * hh + 2], sacc[c][8 * hh + 3]);
                unsigned int W2 = cvt_pk_bf16(sacc[c][8 * hh + 4], sacc[c][8 * hh + 5]);
                unsigned int W3 = cvt_pk_bf16(sacc[c][8 * hh + 6], sacc[c][8 * hh + 7]);
                asm volatile("v_permlane32_swap_b32 %0, %1" : "+v"(W0), "+v"(W2));
                asm volatile("v_permlane32_swap_b32 %0, %1" : "+v"(W1), "+v"(W3));
                union { unsigned int u[4]; bf16x8 v8; } fu;
                fu.u[0] = W0; fu.u[1] = W1; fu.u[2] = W2; fu.u[3] = W3;
                const int kc = c * 2 + hh;
                const int gA = ((kc * 2 + hv) ^ (l32 & 15)) * 8;
                bf16x8 bv0 = *(const bf16x8*)&Vts[cur][l32 * 128 + gA];
                bf16x8 bv1 = *(const bf16x8*)&Vts[cur][(l32 + 32) * 128 + gA];
                o0 = MFMA32(fu.v8, bv0, o0);
                o1 = MFMA32(fu.v8, bv1, o1);
            }
        }
        __builtin_amdgcn_s_setprio(0);
    }
    #undef STAGE

    // epilogue: complete lsum across hv halves, divide, store ctx
    const float lfull = lacc + __shfl_xor(lacc, 32);
    const float inv = 1.f / lfull;
    #pragma unroll
    for (int r = 0; r < 16; r++) {
        const int rloc = (r & 3) + 8 * (r >> 2) + 4 * hv;
        const float invr = __shfl(inv, rloc);       // lane rloc holds q-row rloc
        const int srow = t * 128 + w * 32 + rloc;
        const size_t rowoff = ((size_t)(b * 2048 + srow)) * 1024 + h * 64;
        ctxb[rowoff + l32]      = (bf16)(o0[r] * invr);
        ctxb[rowoff + 32 + l32] = (bf16)(o1[r] * invr);
    }
}

// ---------------------------------------------------------------------------
// Output projection, 64x128 tile, BK=64 (16 iters), 3 blocks/CU,
// XOR-swizzled LDS (granule ^= row&7): 2-way max on reads.
// ---------------------------------------------------------------------------
__global__ __launch_bounds__(256, 3) void oproj_mfma_kernel(
    const bf16* __restrict__ ctxb, const bf16* __restrict__ wob,
    const float* __restrict__ b_out, float* __restrict__ out)
{
    __shared__ bf16 As[2][64 * 64];       // 16KB
    __shared__ bf16 Bs[2][128 * 64];      // 32KB
    const int mt = blockIdx.x;            // 64
    const int nt = blockIdx.y;            // 8
    const int t = threadIdx.x;
    const int w = t >> 6, lane = t & 63, quad = lane >> 4, l16 = lane & 15;
    const int srow8 = lane >> 3;          // 0..7 within 8-row chunk
    const int scg = ((lane & 7) ^ srow8) * 8;   // swizzled src granule (elems)

    const int wrow = (w >> 1) * 32;       // wave row offset (0 / 32)
    const int wcol = (w & 1) * 64;        // wave col offset (0 / 64)

    const bf16* Ab = ctxb + (size_t)(mt * 64) * 1024;
    const bf16* Bb = wob + (size_t)(nt * 128) * 1024;

    f32x4 acc[2][4];
    #pragma unroll
    for (int i = 0; i < 2; i++)
        #pragma unroll
        for (int j = 0; j < 4; j++)
            #pragma unroll
            for (int r = 0; r < 4; r++) acc[i][j][r] = 0.f;

    #define OSTG(buf, kk)                                                     \
        {                                                                     \
            gll16(Ab + (size_t)(w * 8 + srow8) * 1024 + (kk) + scg,           \
                  As[buf] + w * 512);                                         \
            gll16(Ab + (size_t)((w + 4) * 8 + srow8) * 1024 + (kk) + scg,     \
                  As[buf] + (w + 4) * 512);                                   \
            _Pragma("unroll")                                                 \
            for (int c = 0; c < 4; c++) {                                     \
                const int ch = w + 4 * c;                                     \
                gll16(Bb + (size_t)(ch * 8 + srow8) * 1024 + (kk) + scg,      \
                      Bs[buf] + ch * 512);                                    \
            }                                                                 \
        }

    OSTG(0, 0);

    for (int it = 0; it < 16; it++) {
        const int cur = it & 1, nxt = cur ^ 1;
        __syncthreads();
        if (it < 15) { OSTG(nxt, it * 64 + 64); }
        bf16x8 af[2][2], bfv[4][2];
        #pragma unroll
        for (int i = 0; i < 2; i++) {
            const int ro = wrow + i * 16 + l16;
            af[i][0] = *(const bf16x8*)&As[cur][ro * 64 + ((quad)     ^ (ro & 7)) * 8];
            af[i][1] = *(const bf16x8*)&As[cur][ro * 64 + ((quad + 4) ^ (ro & 7)) * 8];
        }
        #pragma unroll
        for (int j = 0; j < 4; j++) {
            const int ro = wcol + j * 16 + l16;
            bfv[j][0] = *(const bf16x8*)&Bs[cur][ro * 64 + ((quad)     ^ (ro & 7)) * 8];
            bfv[j][1] = *(const bf16x8*)&Bs[cur][ro * 64 + ((quad + 4) ^ (ro & 7)) * 8];
        }
        #pragma unroll
        for (int i = 0; i < 2; i++)
            #pragma unroll
            for (int j = 0; j < 4; j++) {
                acc[i][j] = MFMA16(af[i][0], bfv[j][0], acc[i][j]);
                acc[i][j] = MFMA16(af[i][1], bfv[j][1], acc[i][j]);
            }
    }
    #undef OSTG

    #pragma unroll
    for (int i = 0; i < 2; i++)
        #pragma unroll
        for (int j = 0; j < 4; j++)
            #pragma unroll
            for (int r = 0; r < 4; r++) {
                const int m = mt * 64 + wrow + i * 16 + quad * 4 + r;
                const int n = nt * 128 + wcol + j * 16 + l16;
                out[(size_t)m * 1024 + n] = acc[i][j][r] + b_out[n];
            }
}

// ---------------------------------------------------------------------------
extern "C" void kernel_launch(void* const* d_in, const int* in_sizes, int n_in,
                              void* d_out, int out_size, void* d_ws, size_t ws_size,
                              hipStream_t stream)
{
    const float* x     = (const float*)d_in[0];
    // d_in[1] = attn_mask: exact causal tril -> applied analytically, unused
    const float* wq    = (const float*)d_in[2];
    const float* wk    = (const float*)d_in[3];
    const float* wv    = (const float*)d_in[4];
    const float* w_out = (const float*)d_in[5];
    const float* b_out = (const float*)d_in[6];
    float* out = (float*)d_out;

    char* ws = (char*)d_ws;
    bf16* xb   = (bf16*)(ws);                     //  8 MB  (4096x1024)
    bf16* wqb  = (bf16*)(ws + (8u  << 20));       //  2 MB (pre-scaled, log2e folded)
    bf16* wkb  = (bf16*)(ws + (10u << 20));       //  2 MB
    bf16* wvb  = (bf16*)(ws + (12u << 20));       //  2 MB
    bf16* wob  = (bf16*)(ws + (14u << 20));       //  2 MB
    bf16* Qb   = (bf16*)(ws + (16u << 20));       //  8 MB  (B,H,S,64)
    bf16* Kb   = (bf16*)(ws + (24u << 20));       //  8 MB  (B,H,S,64)
    bf16* Vtb  = (bf16*)(ws + (32u << 20));       //  8 MB  (B,H,64,S)
    bf16* ctxb = (bf16*)(ws + (40u << 20));       //  8 MB  (B,S,1024)

    cvt_all_kernel<<<2048, 256, 0, stream>>>(x, wq, wk, wv, w_out,
                                             xb, wqb, wkb, wvb, wob);
    qkv_mfma_kernel<<<dim3(32, 24), 256, 0, stream>>>(xb, wqb, wkb, wvb, Qb, Kb, Vtb);
    attn_mfma_kernel<<<512, 256, 0, stream>>>(Qb, Kb, Vtb, ctxb);
    oproj_mfma_kernel<<<dim3(64, 8), 256, 0, stream>>>(ctxb, wob, b_out, out);
}

// Round 9
// 176.987 us; speedup vs baseline: 1.0141x; 1.0141x over previous
//
#include <hip/hip_runtime.h>
#include <math.h>

// B=2, S=2048, D_IN=1024, H=16, DA=DH=64, EMBED=1024, KSIZE=1 (conv == GEMM)

typedef __bf16 bf16;
typedef __bf16 bf16x8 __attribute__((ext_vector_type(8)));
typedef __bf16 bf16x4 __attribute__((ext_vector_type(4)));
typedef float  f32x4  __attribute__((ext_vector_type(4)));
typedef float  f32x16 __attribute__((ext_vector_type(16)));

#define MFMA16(a, b, c) __builtin_amdgcn_mfma_f32_16x16x32_bf16((a), (b), (c), 0, 0, 0)
#define MFMA32(a, b, c) __builtin_amdgcn_mfma_f32_32x32x16_bf16((a), (b), (c), 0, 0, 0)

__device__ __forceinline__ void gll16(const void* g, void* l) {
    __builtin_amdgcn_global_load_lds(
        (__attribute__((address_space(1))) unsigned int*)g,
        (__attribute__((address_space(3))) unsigned int*)l, 16, 0, 0);
}

__device__ __forceinline__ unsigned int cvt_pk_bf16(float lo, float hi) {
    unsigned int r;
    asm("v_cvt_pk_bf16_f32 %0, %1, %2" : "=v"(r) : "v"(lo), "v"(hi));
    return r;
}

// ---------------------------------------------------------------------------
// fp32->bf16 convert; wq gets 0.125*log2(e) folded (attn uses exp2).
// ---------------------------------------------------------------------------
__global__ __launch_bounds__(256) void cvt_all_kernel(
    const float* __restrict__ x,  const float* __restrict__ wq,
    const float* __restrict__ wk, const float* __restrict__ wv,
    const float* __restrict__ wo,
    bf16* __restrict__ xb,  bf16* __restrict__ wqb, bf16* __restrict__ wkb,
    bf16* __restrict__ wvb, bf16* __restrict__ wob)
{
    #pragma unroll
    for (int k = 0; k < 4; k++) {
        const int blk = blockIdx.x * 4 + k;   // 0..8191 virtual block
        const float* src; bf16* dst; int off; float scale = 1.f;
        if (blk < 4096)      { src = x;  dst = xb;  off = blk * 1024; }
        else if (blk < 5120) { src = wq; dst = wqb; off = (blk - 4096) * 1024;
                               scale = 0.18033688011112042f; }  // 0.125*log2(e)
        else if (blk < 6144) { src = wk; dst = wkb; off = (blk - 5120) * 1024; }
        else if (blk < 7168) { src = wv; dst = wvb; off = (blk - 6144) * 1024; }
        else                 { src = wo; dst = wob; off = (blk - 7168) * 1024; }
        const int i = off + threadIdx.x * 4;
        f32x4 v = *(const f32x4*)(src + i);
        bf16x4 o;
        o[0] = (bf16)(v[0] * scale); o[1] = (bf16)(v[1] * scale);
        o[2] = (bf16)(v[2] * scale); o[3] = (bf16)(v[3] * scale);
        *(bf16x4*)(dst + i) = o;
    }
}

// ---------------------------------------------------------------------------
// QKV GEMM, double-buffered 2-phase, 128x128 tile, BK=32, 3 blocks/CU.
// LDS XOR swizzle granule' = q ^ ((row>>1)&3) on staging src + reads.
// ---------------------------------------------------------------------------
__global__ __launch_bounds__(256, 3) void qkv_mfma_kernel(
    const bf16* __restrict__ xb, const bf16* __restrict__ wqb,
    const bf16* __restrict__ wkb, const bf16* __restrict__ wvb,
    bf16* __restrict__ Qb, bf16* __restrict__ Kb, bf16* __restrict__ Vtb)
{
    __shared__ bf16 As[2][128 * 32];
    __shared__ bf16 Bs[2][128 * 32];
    // bijective XCD-chunk remap (768 = 8 XCD * 96 blocks)
    const int lin = blockIdx.x + 32 * blockIdx.y;   // dispatch-linear id
    const int xcd = lin & 7, lid = lin >> 3;        // xcd = hw XCD (id % 8)
    const int rem = xcd * 96 + lid;                 // contiguous per XCD
    const int mt = rem & 31;                        // 32 row tiles
    const int nt = rem >> 5;                        // 24 = which*8 + coltile
    const int which = nt >> 3;
    const bf16* Wm = (which == 0) ? wqb : (which == 1) ? wkb : wvb;

    const int t = threadIdx.x;
    const int w = t >> 6, lane = t & 63, quad = lane >> 4, l16 = lane & 15;
    const int wm = (w >> 1) * 64, wn = (w & 1) * 64;
    const int srow = lane >> 2;
    const int scol = ((lane & 3) ^ ((lane >> 3) & 3)) * 8;
    const int gx = (l16 >> 1) & 3;        // read-side XOR term

    const bf16* Ab = xb + ((size_t)(mt * 128) + srow) * 1024;
    const bf16* Bb = Wm + ((size_t)((nt & 7) * 128) + srow) * 1024;

    f32x4 acc[4][4];
    #pragma unroll
    for (int i = 0; i < 4; i++)
        #pragma unroll
        for (int j = 0; j < 4; j++)
            #pragma unroll
            for (int r = 0; r < 4; r++) acc[i][j][r] = 0.f;

    gll16(Ab + (size_t)(w * 16) * 1024 + scol,       As[0] + w * 512);
    gll16(Ab + (size_t)((w + 4) * 16) * 1024 + scol, As[0] + (w + 4) * 512);
    gll16(Bb + (size_t)(w * 16) * 1024 + scol,       Bs[0] + w * 512);
    gll16(Bb + (size_t)((w + 4) * 16) * 1024 + scol, Bs[0] + (w + 4) * 512);

    for (int it = 0; it < 32; it++) {
        const int cur = it & 1, nxt = cur ^ 1;
        __syncthreads();
        if (it < 31) {
            const int kn = it * 32 + 32;
            gll16(Ab + (size_t)(w * 16) * 1024 + kn + scol,       As[nxt] + w * 512);
            gll16(Ab + (size_t)((w + 4) * 16) * 1024 + kn + scol, As[nxt] + (w + 4) * 512);
            gll16(Bb + (size_t)(w * 16) * 1024 + kn + scol,       Bs[nxt] + w * 512);
            gll16(Bb + (size_t)((w + 4) * 16) * 1024 + kn + scol, Bs[nxt] + (w + 4) * 512);
        }
        bf16x8 af[4], bfr[4];
        #pragma unroll
        for (int i = 0; i < 4; i++)
            af[i] = *(const bf16x8*)&As[cur][(wm + i * 16 + l16) * 32 +
                                             (quad ^ gx) * 8];
        #pragma unroll
        for (int j = 0; j < 4; j++)
            bfr[j] = *(const bf16x8*)&Bs[cur][(wn + j * 16 + l16) * 32 +
                                              (quad ^ gx) * 8];
        #pragma unroll
        for (int i = 0; i < 4; i++)
            #pragma unroll
            for (int j = 0; j < 4; j++)
                acc[i][j] = MFMA16(af[i], bfr[j], acc[i][j]);
    }

    const int nbase = (nt & 7) * 128 + wn;
    if (which == 2) {
        #pragma unroll
        for (int i = 0; i < 4; i++) {
            const int m0 = mt * 128 + wm + i * 16 + quad * 4;
            const int bb = m0 >> 11, s0 = m0 & 2047;
            #pragma unroll
            for (int j = 0; j < 4; j++) {
                const int n = nbase + j * 16 + l16;
                const int h = n >> 6, d = n & 63;
                bf16x4 pk;
                #pragma unroll
                for (int r = 0; r < 4; r++) pk[r] = (bf16)acc[i][j][r];
                *(bf16x4*)&Vtb[(((size_t)(bb * 16 + h)) * 64 + d) * 2048 + s0] = pk;
            }
        }
    } else {
        bf16* Out = (which == 0) ? Qb : Kb;
        #pragma unroll
        for (int i = 0; i < 4; i++) {
            #pragma unroll
            for (int r = 0; r < 4; r++) {
                const int m = mt * 128 + wm + i * 16 + quad * 4 + r;
                const int bb = m >> 11, s = m & 2047;
                #pragma unroll
                for (int j = 0; j < 4; j++) {
                    const int n = nbase + j * 16 + l16;
                    const int h = n >> 6, d = n & 63;
                    Out[(((size_t)(bb * 16 + h)) * 2048 + s) * 64 + d] =
                        (bf16)acc[i][j][r];
                }
            }
        }
    }
}

// ---------------------------------------------------------------------------
// Attention v9 (R7 configuration — measured best, 177.97 us total).
// 32x32x16 MFMA, P fully in registers (cvt_pk + permlane32_swap, T12).
// R8 A/B showed the t-remap is a no-op (attn is NOT imbalance-bound); the
// kernel sits at its LDS floor given the structural 4-way bank aliasing of
// the MFMA32 A-operand read (32 rows x 1 granule; counting floor, no
// swizzle can fix). Map reverted to R7's (measured best).
// LDS: Ks[2][128x64] + Vts[2][64x128] = 64KB -> 2 blocks/CU.
// ---------------------------------------------------------------------------
__global__ __launch_bounds__(256, 2) void attn_mfma_kernel(
    const bf16* __restrict__ Qb, const bf16* __restrict__ Kb,
    const bf16* __restrict__ Vtb, bf16* __restrict__ ctxb)
{
    __shared__ bf16 Ks[2][128 * 64];      // 128 keys x 64 d (row=key, 128B)
    __shared__ bf16 Vts[2][64 * 128];     // 64 d x 128 keys (row=d, 256B)

    const int g = blockIdx.x;             // 512
    const int base = g & 255;
    const int bh = base & 31;
    const int tp = base >> 5;             // 0..7
    const int t  = (g < 256) ? tp : 15 - tp;
    const int h = bh & 15, b = bh >> 4;
    const int tid = threadIdx.x;
    const int w = tid >> 6, lane = tid & 63;
    const int l32 = lane & 31, hv = lane >> 5;

    const size_t hb = (size_t)(b * 16 + h);
    const bf16* Qh = Qb + hb * (2048 * 64);
    const bf16* Kh = Kb + hb * (2048 * 64);
    const bf16* Vh = Vtb + hb * (64 * 2048);

    const int qrow = t * 128 + w * 32 + l32;  // lane's q-row (B-col / mask ref)

    // Q B-frags (kt-invariant): frag ks covers k(d) = ks*16 + hv*8 + e
    bf16x8 qf[4];
    #pragma unroll
    for (int ks = 0; ks < 4; ks++)
        qf[ks] = *(const bf16x8*)(Qh + (size_t)qrow * 64 + ks * 16 + hv * 8);

    f32x16 o0, o1, zero16;
    #pragma unroll
    for (int r = 0; r < 16; r++) { o0[r] = 0.f; o1[r] = 0.f; zero16[r] = 0.f; }
    float lacc = 0.f;

    // staging lanes
    const int ksr = lane >> 3, ksc = lane & 7;    // K chunk: 8 rows x 8 pos(16B)
    const int vsr = lane >> 4, vsc = lane & 15;   // V chunk: 4 rows x 16 pos(16B)

    #define STAGE(ktv, buf)                                                   \
        {                                                                     \
            _Pragma("unroll")                                                 \
            for (int j = 0; j < 4; j++) {                                     \
                const int c = 4 * w + j;                                      \
                const int kr = c * 8 + ksr;                                   \
                gll16(Kh + (size_t)((ktv) * 128 + kr) * 64 +                  \
                          ((ksc ^ (kr & 7)) * 8),                             \
                      Ks[buf] + c * 512);                                     \
                const int vr = c * 4 + vsr;                                   \
                gll16(Vh + (size_t)vr * 2048 + (ktv) * 128 +                  \
                          ((vsc ^ (vr & 15)) * 8),                            \
                      Vts[buf] + c * 512);                                    \
            }                                                                 \
        }

    STAGE(0, 0);

    for (int v = 0; v <= t; v++) {
        const int cur = v & 1;
        __syncthreads();                  // staging for cur drained; nxt free
        if (v < t) STAGE(v + 1, cur ^ 1);
        const bool diag = (v == t);

        // QK^T: S[key 0..127][q 0..31] for this wave's 32 q-rows
        f32x16 sacc[4];
        const int rowx = l32 & 7;
        __builtin_amdgcn_s_setprio(1);
        #pragma unroll
        for (int c = 0; c < 4; c++) {
            const int key = c * 32 + l32;
            bf16x8 kf0 = *(const bf16x8*)&Ks[cur][key * 64 + ((hv ^ rowx) * 8)];
            sacc[c] = MFMA32(kf0, qf[0], zero16);
            #pragma unroll
            for (int ks = 1; ks < 4; ks++) {
                bf16x8 kf = *(const bf16x8*)&Ks[cur][key * 64 +
                                (((ks * 2 + hv) ^ rowx) * 8)];
                sacc[c] = MFMA32(kf, qf[ks], sacc[c]);
            }
        }
        __builtin_amdgcn_s_setprio(0);

        // exp2 + causal mask (diag tile only) + per-lane lsum partial
        #pragma unroll
        for (int c = 0; c < 4; c++) {
            #pragma unroll
            for (int r = 0; r < 16; r++) {
                float p = __builtin_amdgcn_exp2f(sacc[c][r]);
                if (diag) {
                    const int key = v * 128 + c * 32 + (r & 3) + 8 * (r >> 2)
                                    + 4 * hv;
                    if (key > qrow) p = 0.f;
                }
                sacc[c][r] = p;
                lacc += p;
            }
        }

        // PV: per 16-key chunk build A-frag in registers, 2 V-frags, 2 MFMA
        __builtin_amdgcn_s_setprio(1);
        #pragma unroll
        for (int c = 0; c < 4; c++) {
            #pragma unroll
            for (int hh = 0; hh < 2; hh++) {
                unsigned int W0 = cvt_pk_bf16(sacc[c][8 * hh + 0], sacc[c][8 * hh + 1]);
                unsigned int W1 = cvt_pk_bf16(sacc[c][8 * hh + 2], sacc[c][8 * hh + 3]);
                unsigned int W2 = cvt_pk_bf16(sacc[c][8 * hh + 4], sacc[c][8 * hh + 5]);
                unsigned int W3 = cvt_pk_bf16(sacc[c][8 * hh + 6], sacc[c][8 * hh + 7]);
                asm volatile("v_permlane32_swap_b32 %0, %1" : "+v"(W0), "+v"(W2));
                asm volatile("v_permlane32_swap_b32 %0, %1" : "+v"(W1), "+v"(W3));
                union { unsigned int u[4]; bf16x8 v8; } fu;
                fu.u[0] = W0; fu.u[1] = W1; fu.u[2] = W2; fu.u[3] = W3;
                const int kc = c * 2 + hh;
                const int gA = ((kc * 2 + hv) ^ (l32 & 15)) * 8;
                bf16x8 bv0 = *(const bf16x8*)&Vts[cur][l32 * 128 + gA];
                bf16x8 bv1 = *(const bf16x8*)&Vts[cur][(l32 + 32) * 128 + gA];
                o0 = MFMA32(fu.v8, bv0, o0);
                o1 = MFMA32(fu.v8, bv1, o1);
            }
        }
        __builtin_amdgcn_s_setprio(0);
    }
    #undef STAGE

    // epilogue: complete lsum across hv halves, divide, store ctx
    const float lfull = lacc + __shfl_xor(lacc, 32);
    const float inv = 1.f / lfull;
    #pragma unroll
    for (int r = 0; r < 16; r++) {
        const int rloc = (r & 3) + 8 * (r >> 2) + 4 * hv;
        const float invr = __shfl(inv, rloc);       // lane rloc holds q-row rloc
        const int srow = t * 128 + w * 32 + rloc;
        const size_t rowoff = ((size_t)(b * 2048 + srow)) * 1024 + h * 64;
        ctxb[rowoff + l32]      = (bf16)(o0[r] * invr);
        ctxb[rowoff + 32 + l32] = (bf16)(o1[r] * invr);
    }
}

// ---------------------------------------------------------------------------
// Output projection, 64x128 tile, BK=64 (16 iters), 3 blocks/CU,
// XOR-swizzled LDS (granule ^= row&7): 2-way max on reads.
// ---------------------------------------------------------------------------
__global__ __launch_bounds__(256, 3) void oproj_mfma_kernel(
    const bf16* __restrict__ ctxb, const bf16* __restrict__ wob,
    const float* __restrict__ b_out, float* __restrict__ out)
{
    __shared__ bf16 As[2][64 * 64];       // 16KB
    __shared__ bf16 Bs[2][128 * 64];      // 32KB
    const int mt = blockIdx.x;            // 64
    const int nt = blockIdx.y;            // 8
    const int t = threadIdx.x;
    const int w = t >> 6, lane = t & 63, quad = lane >> 4, l16 = lane & 15;
    const int srow8 = lane >> 3;          // 0..7 within 8-row chunk
    const int scg = ((lane & 7) ^ srow8) * 8;   // swizzled src granule (elems)

    const int wrow = (w >> 1) * 32;       // wave row offset (0 / 32)
    const int wcol = (w & 1) * 64;        // wave col offset (0 / 64)

    const bf16* Ab = ctxb + (size_t)(mt * 64) * 1024;
    const bf16* Bb = wob + (size_t)(nt * 128) * 1024;

    f32x4 acc[2][4];
    #pragma unroll
    for (int i = 0; i < 2; i++)
        #pragma unroll
        for (int j = 0; j < 4; j++)
            #pragma unroll
            for (int r = 0; r < 4; r++) acc[i][j][r] = 0.f;

    #define OSTG(buf, kk)                                                     \
        {                                                                     \
            gll16(Ab + (size_t)(w * 8 + srow8) * 1024 + (kk) + scg,           \
                  As[buf] + w * 512);                                         \
            gll16(Ab + (size_t)((w + 4) * 8 + srow8) * 1024 + (kk) + scg,     \
                  As[buf] + (w + 4) * 512);                                   \
            _Pragma("unroll")                                                 \
            for (int c = 0; c < 4; c++) {                                     \
                const int ch = w + 4 * c;                                     \
                gll16(Bb + (size_t)(ch * 8 + srow8) * 1024 + (kk) + scg,      \
                      Bs[buf] + ch * 512);                                    \
            }                                                                 \
        }

    OSTG(0, 0);

    for (int it = 0; it < 16; it++) {
        const int cur = it & 1, nxt = cur ^ 1;
        __syncthreads();
        if (it < 15) { OSTG(nxt, it * 64 + 64); }
        bf16x8 af[2][2], bfv[4][2];
        #pragma unroll
        for (int i = 0; i < 2; i++) {
            const int ro = wrow + i * 16 + l16;
            af[i][0] = *(const bf16x8*)&As[cur][ro * 64 + ((quad)     ^ (ro & 7)) * 8];
            af[i][1] = *(const bf16x8*)&As[cur][ro * 64 + ((quad + 4) ^ (ro & 7)) * 8];
        }
        #pragma unroll
        for (int j = 0; j < 4; j++) {
            const int ro = wcol + j * 16 + l16;
            bfv[j][0] = *(const bf16x8*)&Bs[cur][ro * 64 + ((quad)     ^ (ro & 7)) * 8];
            bfv[j][1] = *(const bf16x8*)&Bs[cur][ro * 64 + ((quad + 4) ^ (ro & 7)) * 8];
        }
        #pragma unroll
        for (int i = 0; i < 2; i++)
            #pragma unroll
            for (int j = 0; j < 4; j++) {
                acc[i][j] = MFMA16(af[i][0], bfv[j][0], acc[i][j]);
                acc[i][j] = MFMA16(af[i][1], bfv[j][1], acc[i][j]);
            }
    }
    #undef OSTG

    #pragma unroll
    for (int i = 0; i < 2; i++)
        #pragma unroll
        for (int j = 0; j < 4; j++)
            #pragma unroll
            for (int r = 0; r < 4; r++) {
                const int m = mt * 64 + wrow + i * 16 + quad * 4 + r;
                const int n = nt * 128 + wcol + j * 16 + l16;
                out[(size_t)m * 1024 + n] = acc[i][j][r] + b_out[n];
            }
}

// ---------------------------------------------------------------------------
extern "C" void kernel_launch(void* const* d_in, const int* in_sizes, int n_in,
                              void* d_out, int out_size, void* d_ws, size_t ws_size,
                              hipStream_t stream)
{
    const float* x     = (const float*)d_in[0];
    // d_in[1] = attn_mask: exact causal tril -> applied analytically, unused
    const float* wq    = (const float*)d_in[2];
    const float* wk    = (const float*)d_in[3];
    const float* wv    = (const float*)d_in[4];
    const float* w_out = (const float*)d_in[5];
    const float* b_out = (const float*)d_in[6];
    float* out = (float*)d_out;

    char* ws = (char*)d_ws;
    bf16* xb   = (bf16*)(ws);                     //  8 MB  (4096x1024)
    bf16* wqb  = (bf16*)(ws + (8u  << 20));       //  2 MB (pre-scaled, log2e folded)
    bf16* wkb  = (bf16*)(ws + (10u << 20));       //  2 MB
    bf16* wvb  = (bf16*)(ws + (12u << 20));       //  2 MB
    bf16* wob  = (bf16*)(ws + (14u << 20));       //  2 MB
    bf16* Qb   = (bf16*)(ws + (16u << 20));       //  8 MB  (B,H,S,64)
    bf16* Kb   = (bf16*)(ws + (24u << 20));       //  8 MB  (B,H,S,64)
    bf16* Vtb  = (bf16*)(ws + (32u << 20));       //  8 MB  (B,H,64,S)
    bf16* ctxb = (bf16*)(ws + (40u << 20));       //  8 MB  (B,S,1024)

    cvt_all_kernel<<<2048, 256, 0, stream>>>(x, wq, wk, wv, w_out,
                                             xb, wqb, wkb, wvb, wob);
    qkv_mfma_kernel<<<dim3(32, 24), 256, 0, stream>>>(xb, wqb, wkb, wvb, Qb, Kb, Vtb);
    attn_mfma_kernel<<<512, 256, 0, stream>>>(Qb, Kb, Vtb, ctxb);
    oproj_mfma_kernel<<<dim3(64, 8), 256, 0, stream>>>(ctxb, wob, b_out, out);
}